// Round 7
// baseline (126.552 us; speedup 1.0000x reference)
//
#include <hip/hip_runtime.h>
#include <hip/hip_bf16.h>

typedef unsigned short u16;
typedef unsigned int   u32;
typedef unsigned long long u64;
typedef __attribute__((ext_vector_type(8)))  __bf16 bf16x8;
typedef __attribute__((ext_vector_type(4)))  float  f32x4;
typedef __attribute__((ext_vector_type(16))) float  f32x16;
typedef __attribute__((ext_vector_type(8)))  u16    ushort8;
typedef __attribute__((ext_vector_type(4)))  u32    u32x4;

#define S_LEN 2048
#define D_DIM 64
#define NBH   32
#define SD    131072
#define MROW  32
#define MB_PB 65536
#define NT    32            // KV tiles of 64

#define VTS   2080          // V^T row stride in u16 (4160B = 65 cache lines; odd -> breaks L1 sets)
#define VT_BH 133120        // 64 * VTS  (u16 per bh)

// workspace layout (bytes): Kb 8.39MB | Vt 8.52MB | Mb 1MB | pad
#define KB_OFF 0u
#define VT_OFF 8388608u
#define MB_OFF 16908288u     // VT_OFF + 32*VT_BH*2 = 8388608 + 8519680
#define WS_NEED 18087936u    // MB_OFF + 1MB + 128KB pad

#define QSCALE 0.18033688011112042f   // 0.125 * log2(e) -> scores in log2 domain

static __device__ __forceinline__ u16 f2bf(float f) {
  u32 u = __builtin_bit_cast(u32, f);
  u += 0x7fffu + ((u >> 16) & 1u);
  return (u16)(u >> 16);
}

static __device__ __forceinline__ u32 cvtpk(float lo, float hi) {
  u32 d;
  asm("v_cvt_pk_bf16_f32 %0, %1, %2" : "=v"(d) : "v"(lo), "v"(hi));
  return d;
}
// ONLY safe when a and b are distinct SSA values (regalloc may alias equal
// values to one VGPR -> in-place half-swap). Equal-value exchange: __shfl_xor.
static __device__ __forceinline__ void plswap(u32& a, u32& b) {
  asm volatile("v_permlane32_swap_b32 %0, %1" : "+v"(a), "+v"(b));
}

// ---------------- fused prep kernel ----------------
// blocks [0,2048): K f32->bf16 ; [2048,3072): V -> V^T bf16 (stride VTS) ;
// [3072,35840): mask bitpack
__global__ __launch_bounds__(256) void prep_all(
    const float* __restrict__ K, const float* __restrict__ V, const int* __restrict__ M,
    u16* __restrict__ Kb, u16* __restrict__ Vt, u64* __restrict__ Mb) {
  const int bx = blockIdx.x, tid = threadIdx.x;
  if (bx < 2048) {
    size_t i = ((size_t)bx * 256 + tid) * 8;
    float4 a = *reinterpret_cast<const float4*>(K + i);
    float4 b = *reinterpret_cast<const float4*>(K + i + 4);
    ushort8 u;
    u[0]=f2bf(a.x); u[1]=f2bf(a.y); u[2]=f2bf(a.z); u[3]=f2bf(a.w);
    u[4]=f2bf(b.x); u[5]=f2bf(b.y); u[6]=f2bf(b.z); u[7]=f2bf(b.w);
    *reinterpret_cast<ushort8*>(Kb + i) = u;
  } else if (bx < 3072) {
    __shared__ u16 t[64][72];
    const int idx = bx - 2048;
    const int bh = idx >> 5, s0 = (idx & 31) * 64;
    const float* src = V + ((size_t)bh * S_LEN + s0) * D_DIM;
    const int r = tid >> 2, c0 = (tid & 3) * 16;
#pragma unroll
    for (int i = 0; i < 16; i += 4) {
      float4 x = *reinterpret_cast<const float4*>(src + r * 64 + c0 + i);
      t[r][c0+i]   = f2bf(x.x); t[r][c0+i+1] = f2bf(x.y);
      t[r][c0+i+2] = f2bf(x.z); t[r][c0+i+3] = f2bf(x.w);
    }
    __syncthreads();
    u16* dst = Vt + (size_t)bh * VT_BH + s0;
#pragma unroll
    for (int qq = 0; qq < 2; ++qq) {
      int q = tid * 2 + qq;
      int d = q >> 3, so = (q & 7) * 8;
      ushort8 u;
#pragma unroll
      for (int j = 0; j < 8; ++j) u[j] = t[so + j][d];
      *reinterpret_cast<ushort8*>(dst + (size_t)d * VTS + so) = u;
    }
  } else {
    int g = (bx - 3072) * 256 + tid;
    int lane = g & 63;
    int v = M[(size_t)g];
    u64 bits = __ballot(v != 0);
    if (lane == 0) Mb[g >> 6] = bits;
  }
}

// ---------------- main kernel (v7): zero-LDS main loop ----------------
// Swapped-operand 32x32 MFMA, in-register softmax (no row-max), K/V fragments
// loaded DIRECTLY global->VGPR (L1/L2-served), K double-buffered 1 iter ahead.
// No staging, no syncthreads; bare s_barrier/iter keeps waves lockstep for L1.

static __device__ __forceinline__ void loadK(bf16x8 (&Kf)[8], const u16* kp) {
#pragma unroll
  for (int s = 0; s < 4; ++s) {
    Kf[s]     = *reinterpret_cast<const bf16x8*>(kp + s * 16 - 1024);  // kv rows 0-31
    Kf[s + 4] = *reinterpret_cast<const bf16x8*>(kp + s * 16 + 1024);  // kv rows 32-63
  }
}

static __device__ __forceinline__ void iter_body(
    const bf16x8 (&Kf)[8], const u16* vp0, const u16* vp1, u64 mw,
    const bf16x8 (&Qf)[4], f32x16& accOT0, f32x16& accOT1, float& l_, int hi) {
  const u32 mlo = (u32)mw, mhiw = (u32)(mw >> 32);

  // ---- QK^T (swapped): sT = K[tile] x Q^T, D[kv][q] ----
  f32x16 sT0 = {0,0,0,0,0,0,0,0,0,0,0,0,0,0,0,0};
  f32x16 sT1 = {0,0,0,0,0,0,0,0,0,0,0,0,0,0,0,0};
  __builtin_amdgcn_s_setprio(1);
#pragma unroll
  for (int s = 0; s < 4; ++s) {
    sT0 = __builtin_amdgcn_mfma_f32_32x32x16_bf16(Kf[s],     Qf[s], sT0, 0, 0, 0);
    sT1 = __builtin_amdgcn_mfma_f32_32x32x16_bf16(Kf[s + 4], Qf[s], sT1, 0, 0, 0);
  }
  __builtin_amdgcn_s_setprio(0);

  // ---- issue V-fragment loads (arrive during softmax) ----
  bf16x8 Vf[8];
#pragma unroll
  for (int ks = 0; ks < 4; ++ks) {
    Vf[ks]     = *reinterpret_cast<const bf16x8*>(vp0 + ks * 16);  // d rows 0-31
    Vf[ks + 4] = *reinterpret_cast<const bf16x8*>(vp1 + ks * 16);  // d rows 32-63
  }
  __builtin_amdgcn_sched_barrier(0);   // pin loads above softmax

  // ---- p = exp2(s), mask via sbfe+and, sum, pack to bf16 ----
  float lp0 = 0.f, lp1 = 0.f;
  u32 A0_[8], A1_[8];
#pragma unroll
  for (int T = 0; T < 2; ++T) {
    const f32x16& sv = T ? sT1 : sT0;
    const u32 mword = T ? mhiw : mlo;
#pragma unroll
    for (int j = 0; j < 8; ++j) {
      const int r0 = 2 * j, r1 = 2 * j + 1;
      const int b0 = (r0 & 3) + 8 * (r0 >> 2) + 4 * hi;
      const int b1 = (r1 & 3) + 8 * (r1 >> 2) + 4 * hi;
      float e0 = __builtin_amdgcn_exp2f(sv[r0]);
      float e1 = __builtin_amdgcn_exp2f(sv[r1]);
      int s0 = __builtin_amdgcn_sbfe(mword, b0, 1);
      int s1 = __builtin_amdgcn_sbfe(mword, b1, 1);
      e0 = __builtin_bit_cast(float, __builtin_bit_cast(u32, e0) & (u32)s0);
      e1 = __builtin_bit_cast(float, __builtin_bit_cast(u32, e1) & (u32)s1);
      lp0 += e0; lp1 += e1;
      u32 w = cvtpk(e0, e1);
      if (T == 0) A0_[j] = w; else A1_[j] = w;
    }
  }
  l_ += lp0 + lp1;

  // ---- build PV B-fragments in-register (distinct-operand permlane swaps) ----
  bf16x8 PA[4];
  {
    u32 a, c, b2, d2;
    a = A0_[0]; c = A0_[2]; plswap(a, c);
    b2 = A0_[1]; d2 = A0_[3]; plswap(b2, d2);
    u32x4 w0 = {a, b2, c, d2}; PA[0] = __builtin_bit_cast(bf16x8, w0);
    a = A0_[4]; c = A0_[6]; plswap(a, c);
    b2 = A0_[5]; d2 = A0_[7]; plswap(b2, d2);
    u32x4 w1 = {a, b2, c, d2}; PA[1] = __builtin_bit_cast(bf16x8, w1);
    a = A1_[0]; c = A1_[2]; plswap(a, c);
    b2 = A1_[1]; d2 = A1_[3]; plswap(b2, d2);
    u32x4 w2 = {a, b2, c, d2}; PA[2] = __builtin_bit_cast(bf16x8, w2);
    a = A1_[4]; c = A1_[6]; plswap(a, c);
    b2 = A1_[5]; d2 = A1_[7]; plswap(b2, d2);
    u32x4 w3 = {a, b2, c, d2}; PA[3] = __builtin_bit_cast(bf16x8, w3);
  }

  // ---- PV (swapped): accOT[D0] += V^T[D0-tile] x P^T ----
  __builtin_amdgcn_s_setprio(1);
#pragma unroll
  for (int ks = 0; ks < 4; ++ks) {
    accOT0 = __builtin_amdgcn_mfma_f32_32x32x16_bf16(Vf[ks],     PA[ks], accOT0, 0, 0, 0);
    accOT1 = __builtin_amdgcn_mfma_f32_32x32x16_bf16(Vf[ks + 4], PA[ks], accOT1, 0, 0, 0);
  }
  __builtin_amdgcn_s_setprio(0);

  __builtin_amdgcn_s_barrier();   // bare barrier: wave lockstep for L1 locality
}

__global__ __launch_bounds__(256, 2) void attn_fwd7(
    const float* __restrict__ Q, const u16* __restrict__ Kb,
    const u16* __restrict__ Vt, const u64* __restrict__ Mb,
    float* __restrict__ O) {
  __shared__ __align__(16) float Sc[4 * 1152];   // epilogue bounce only (18KB)

  const int tid  = threadIdx.x;
  const int lane = tid & 63;
  const int wid  = tid >> 6;
  const int l31  = lane & 31;
  const int hi   = lane >> 5;

  const int bh = blockIdx.y, b = bh >> 4;
  const int q0w = blockIdx.x * 128 + wid * 32;
  const size_t base = (size_t)bh * SD;

  // Q fragments: f32 load + scale + pack (once per block)
  bf16x8 Qf[4];
  {
    const float* qsrc = Q + base + (size_t)(q0w + l31) * 64;
#pragma unroll
    for (int s = 0; s < 4; ++s) {
      const int d0 = s * 16 + hi * 8;
      float4 x = *reinterpret_cast<const float4*>(qsrc + d0);
      float4 y = *reinterpret_cast<const float4*>(qsrc + d0 + 4);
      u32x4 w;
      w[0] = cvtpk(x.x * QSCALE, x.y * QSCALE);
      w[1] = cvtpk(x.z * QSCALE, x.w * QSCALE);
      w[2] = cvtpk(y.x * QSCALE, y.y * QSCALE);
      w[3] = cvtpk(y.z * QSCALE, y.w * QSCALE);
      Qf[s] = __builtin_bit_cast(bf16x8, w);
    }
  }

  // per-lane fragment pointers (u16 units); chunk/row-half offsets are imm
  const u16* kpE = Kb + base + l31 * 64 + hi * 8 + 1024;   // +2048B center of 64-row tile
  const u16* kpO = kpE + 4096;                             // +64 kv rows
  const u16* vp0 = Vt + (size_t)bh * VT_BH + (size_t)l31 * VTS + hi * 8;
  const u16* vp1 = vp0 + 32 * VTS;

  const u64* mp = Mb + (size_t)b * MB_PB + (size_t)(q0w + l31) * MROW;

  f32x16 accOT0 = {0,0,0,0,0,0,0,0,0,0,0,0,0,0,0,0};
  f32x16 accOT1 = {0,0,0,0,0,0,0,0,0,0,0,0,0,0,0,0};
  float l_ = 0.f;

  bf16x8 KfA[8], KfB[8];
  loadK(KfA, kpE);                 // K for it=0
  u64 mwC0 = mp[0], mwC1 = mp[1];

#pragma unroll 1
  for (int t = 0; t < 16; ++t) {
    u64 mwN0 = mp[2 * t + 2], mwN1 = mp[2 * t + 3];   // next-trip masks (pad covers t=15)

    loadK(KfB, kpO);               // K for it=2t+1
    iter_body(KfA, vp0, vp1, mwC0, Qf, accOT0, accOT1, l_, hi);

    kpE += 8192; kpO += 8192;
    loadK(KfA, kpE);               // K for it=2t+2 (t=15: in-bounds overshoot into Vt)
    iter_body(KfB, vp0 + 64, vp1 + 64, mwC1, Qf, accOT0, accOT1, l_, hi);

    vp0 += 128; vp1 += 128;
    mwC0 = mwN0; mwC1 = mwN1;
  }

  // ---- epilogue: l across halves, normalize, LDS-bounce transpose, store ----
  l_ += __shfl_xor(l_, 32);
  const float inv = __builtin_amdgcn_rcpf(l_);

  float* sc = Sc + wid * 1152;     // per-wave [32][36] f32
#pragma unroll
  for (int D0 = 0; D0 < 2; ++D0) {
    const f32x16& acc = D0 ? accOT1 : accOT0;
#pragma unroll
    for (int r = 0; r < 16; ++r) {
      const int dloc = (r & 3) + 8 * (r >> 2) + 4 * hi;
      sc[l31 * 36 + dloc] = acc[r] * inv;
    }
    asm volatile("s_waitcnt lgkmcnt(0)" ::: "memory");
    __builtin_amdgcn_sched_barrier(0);
    const int qq = lane >> 1, off = (lane & 1) * 16;
#pragma unroll
    for (int j = 0; j < 4; ++j) {
      float4 x = *reinterpret_cast<const float4*>(&sc[qq * 36 + off + j * 4]);
      *reinterpret_cast<float4*>(O + base + (size_t)(q0w + qq) * 64 + D0 * 32 + off + j * 4) = x;
    }
    asm volatile("s_waitcnt lgkmcnt(0)" ::: "memory");
    __builtin_amdgcn_sched_barrier(0);
  }
}

// ---------------- fallback (round-1 kernel, used if ws too small) ----------------
#define KST 72
#define VST 40
#define PST 40
static __device__ __forceinline__ bf16x8 ld_frag(const u16* p) {
  ushort8 u = *reinterpret_cast<const ushort8*>(p);
  return __builtin_bit_cast(bf16x8, u);
}
__global__ __launch_bounds__(256) void attn_fwd_v1(
    const float* __restrict__ Q, const float* __restrict__ K,
    const float* __restrict__ V, const int* __restrict__ M,
    float* __restrict__ O) {
  __shared__ __align__(16) u16 Klds[32 * KST];
  __shared__ __align__(16) u16 Vlds[64 * VST];
  __shared__ __align__(16) u16 Plds[4 * 16 * PST];
  const int tid = threadIdx.x, lane = tid & 63, wid = tid >> 6;
  const int lrow = lane & 15, lgrp = lane >> 4;
  const int bh = blockIdx.y, b = bh >> 4;
  const int q0 = blockIdx.x * 64 + wid * 16;
  const int base = bh * S_LEN * D_DIM, mbase = b * S_LEN * S_LEN;
  bf16x8 qf[2];
#pragma unroll
  for (int c = 0; c < 2; ++c) {
    const float* src = Q + base + (q0 + lrow) * 64 + c * 32 + lgrp * 8;
    float4 x = *reinterpret_cast<const float4*>(src);
    float4 y = *reinterpret_cast<const float4*>(src + 4);
    ushort8 u;
    u[0]=f2bf(x.x*0.125f); u[1]=f2bf(x.y*0.125f); u[2]=f2bf(x.z*0.125f); u[3]=f2bf(x.w*0.125f);
    u[4]=f2bf(y.x*0.125f); u[5]=f2bf(y.y*0.125f); u[6]=f2bf(y.z*0.125f); u[7]=f2bf(y.w*0.125f);
    qf[c] = __builtin_bit_cast(bf16x8, u);
  }
  f32x4 accO[4];
#pragma unroll
  for (int c = 0; c < 4; ++c) accO[c] = (f32x4){0.f,0.f,0.f,0.f};
  float m_[4] = {-1e9f,-1e9f,-1e9f,-1e9f}, l_[4] = {0.f,0.f,0.f,0.f};
  const int srow = tid >> 3, scol = (tid & 7) * 8;
  for (int kv0 = 0; kv0 < S_LEN; kv0 += 32) {
    __syncthreads();
    {
      const float* src = K + base + (kv0 + srow) * 64 + scol;
      float4 x = *reinterpret_cast<const float4*>(src);
      float4 y = *reinterpret_cast<const float4*>(src + 4);
      ushort8 u;
      u[0]=f2bf(x.x); u[1]=f2bf(x.y); u[2]=f2bf(x.z); u[3]=f2bf(x.w);
      u[4]=f2bf(y.x); u[5]=f2bf(y.y); u[6]=f2bf(y.z); u[7]=f2bf(y.w);
      *reinterpret_cast<ushort8*>(&Klds[srow * KST + scol]) = u;
    }
    {
      const float* src = V + base + (kv0 + srow) * 64 + scol;
      float4 x = *reinterpret_cast<const float4*>(src);
      float4 y = *reinterpret_cast<const float4*>(src + 4);
      float vals[8] = {x.x,x.y,x.z,x.w,y.x,y.y,y.z,y.w};
#pragma unroll
      for (int i = 0; i < 8; ++i) Vlds[(scol + i) * VST + srow] = f2bf(vals[i]);
    }
    __syncthreads();
    f32x4 s0 = (f32x4){0.f,0.f,0.f,0.f}, s1 = (f32x4){0.f,0.f,0.f,0.f};
#pragma unroll
    for (int c = 0; c < 2; ++c) {
      bf16x8 k0 = ld_frag(&Klds[lrow * KST + c * 32 + lgrp * 8]);
      bf16x8 k1 = ld_frag(&Klds[(16 + lrow) * KST + c * 32 + lgrp * 8]);
      s0 = __builtin_amdgcn_mfma_f32_16x16x32_bf16(qf[c], k0, s0, 0, 0, 0);
      s1 = __builtin_amdgcn_mfma_f32_16x16x32_bf16(qf[c], k1, s1, 0, 0, 0);
    }
#pragma unroll
    for (int r = 0; r < 4; ++r) {
      const int moff = mbase + (q0 + lgrp * 4 + r) * S_LEN + kv0 + lrow;
      if (M[moff] == 0)      s0[r] = -1e30f;
      if (M[moff + 16] == 0) s1[r] = -1e30f;
    }
    const int pbase = wid * 16 * PST;
#pragma unroll
    for (int r = 0; r < 4; ++r) {
      float t = fmaxf(s0[r], s1[r]);
      t = fmaxf(t, __shfl_xor(t, 1)); t = fmaxf(t, __shfl_xor(t, 2));
      t = fmaxf(t, __shfl_xor(t, 4)); t = fmaxf(t, __shfl_xor(t, 8));
      float mn = fmaxf(m_[r], t);
      float sf = __expf(m_[r] - mn);
      m_[r] = mn;
      float p0 = __expf(s0[r] - mn), p1 = __expf(s1[r] - mn);
      float su = p0 + p1;
      su += __shfl_xor(su, 1); su += __shfl_xor(su, 2);
      su += __shfl_xor(su, 4); su += __shfl_xor(su, 8);
      l_[r] = l_[r] * sf + su;
      accO[0][r] *= sf; accO[1][r] *= sf; accO[2][r] *= sf; accO[3][r] *= sf;
      const int prow = lgrp * 4 + r;
      Plds[pbase + prow * PST + lrow]      = f2bf(p0);
      Plds[pbase + prow * PST + 16 + lrow] = f2bf(p1);
    }
    asm volatile("s_waitcnt lgkmcnt(0)" ::: "memory");
    __builtin_amdgcn_sched_barrier(0);
    bf16x8 pa = ld_frag(&Plds[pbase + lrow * PST + lgrp * 8]);
#pragma unroll
    for (int c = 0; c < 4; ++c) {
      bf16x8 bv = ld_frag(&Vlds[(c * 16 + lrow) * VST + lgrp * 8]);
      accO[c] = __builtin_amdgcn_mfma_f32_16x16x32_bf16(pa, bv, accO[c], 0, 0, 0);
    }
  }
#pragma unroll
  for (int r = 0; r < 4; ++r) {
    const float inv = 1.0f / l_[r];
    float* dst = O + base + (q0 + lgrp * 4 + r) * 64;
#pragma unroll
    for (int c = 0; c < 4; ++c) dst[c * 16 + lrow] = accO[c][r] * inv;
  }
}

extern "C" void kernel_launch(void* const* d_in, const int* in_sizes, int n_in,
                              void* d_out, int out_size, void* d_ws, size_t ws_size,
                              hipStream_t stream) {
  const float* q = (const float*)d_in[0];
  const float* k = (const float*)d_in[1];
  const float* v = (const float*)d_in[2];
  const int*   m = (const int*)d_in[3];
  float* out = (float*)d_out;

  if (ws_size < (size_t)WS_NEED) {
    dim3 grid(S_LEN / 64, NBH);
    attn_fwd_v1<<<grid, dim3(256), 0, stream>>>(q, k, v, m, out);
    return;
  }

  u16* Kb = (u16*)((char*)d_ws + KB_OFF);
  u16* Vt = (u16*)((char*)d_ws + VT_OFF);
  u64* Mb = (u64*)((char*)d_ws + MB_OFF);

  prep_all<<<dim3(35840), dim3(256), 0, stream>>>(k, v, m, Kb, Vt, Mb);
  attn_fwd7<<<dim3(S_LEN / 128, NBH), dim3(256), 0, stream>>>(q, Kb, Vt, Mb, out);
}

// Round 9
// 77.230 us; speedup vs baseline: 1.6387x; 1.6387x over previous
//
#include <hip/hip_runtime.h>
#include <hip/hip_bf16.h>

typedef unsigned short u16;
typedef unsigned int   u32;
typedef unsigned long long u64;
typedef __attribute__((ext_vector_type(8)))  __bf16 bf16x8;
typedef __attribute__((ext_vector_type(4)))  float  f32x4;
typedef __attribute__((ext_vector_type(16))) float  f32x16;
typedef __attribute__((ext_vector_type(8)))  u16    ushort8;
typedef __attribute__((ext_vector_type(4)))  u32    u32x4;

#define S_LEN 2048
#define D_DIM 64
#define NBH   32
#define SD    131072
#define MROW  32
#define MB_PB 65536
#define NT    32            // KV tiles of 64

// Fragment-linear buffers: per (bh, tile): 512 frags x 16B = 8KB.
// K frag f = s*128 + T*64 + l  -> K[tile*64 + T*32 + (l&31)][s*16 + (l>>5)*8 + 0..7]
// V frag f = ks*128 + D0*64 + l -> V[tile*64 + ks*16 + (l>>5)*8 + j][D0*32 + (l&31)]
#define FR_BH 131072        // u16 per bh (32 tiles * 4096)

// workspace layout (bytes): Kf 8MB | Vf 8MB | Mb 1MB | pad
#define KF_OFF 0u
#define VF_OFF 8388608u
#define MB_OFF 16777216u
#define WS_NEED 17833984u   // MB_OFF + 1MB + 8KB pad (mask prefetch overread)

#define QSCALE 0.18033688011112042f   // 0.125 * log2(e) -> scores in log2 domain

static __device__ __forceinline__ u16 f2bf(float f) {
  u32 u = __builtin_bit_cast(u32, f);
  u += 0x7fffu + ((u >> 16) & 1u);
  return (u16)(u >> 16);
}

static __device__ __forceinline__ void gl16(const void* g, void* l) {
  __builtin_amdgcn_global_load_lds(
      (const __attribute__((address_space(1))) u32*)g,
      (__attribute__((address_space(3))) u32*)l, 16, 0, 0);
}

static __device__ __forceinline__ u32 cvtpk(float lo, float hi) {
  u32 d;
  asm("v_cvt_pk_bf16_f32 %0, %1, %2" : "=v"(d) : "v"(lo), "v"(hi));
  return d;
}
// ONLY safe when a and b are distinct SSA values (regalloc may alias equal
// values to one VGPR -> in-place half-swap). Equal-value exchange: __shfl_xor.
static __device__ __forceinline__ void plswap(u32& a, u32& b) {
  asm volatile("v_permlane32_swap_b32 %0, %1" : "+v"(a), "+v"(b));
}

#define WAITV(N) asm volatile("s_waitcnt vmcnt(" #N ")" ::: "memory")

// ---------------- fused prep kernel ----------------
// bx [0,1024): K tile -> fragment-linear ; [1024,2048): V tile -> frag-linear ;
// [2048,34816): mask bitpack
__global__ __launch_bounds__(256) void prep_all(
    const float* __restrict__ K, const float* __restrict__ V, const int* __restrict__ M,
    u16* __restrict__ Kf, u16* __restrict__ Vf, u64* __restrict__ Mb) {
  const int bx = blockIdx.x, tid = threadIdx.x;
  if (bx < 2048) {
    __shared__ u16 t[64][72];
    const bool isK = bx < 1024;
    const int idx = isK ? bx : bx - 1024;
    const int bh = idx >> 5, tt = idx & 31;
    const float* src = (isK ? K : V) + ((size_t)bh * S_LEN + tt * 64) * D_DIM;
    const int r = tid >> 2, c0 = (tid & 3) * 16;
#pragma unroll
    for (int i = 0; i < 16; i += 4) {
      float4 x = *reinterpret_cast<const float4*>(src + r * 64 + c0 + i);
      t[r][c0+i]   = f2bf(x.x); t[r][c0+i+1] = f2bf(x.y);
      t[r][c0+i+2] = f2bf(x.z); t[r][c0+i+3] = f2bf(x.w);
    }
    __syncthreads();
    u16* dst = (isK ? Kf : Vf) + (size_t)bh * FR_BH + (size_t)tt * 4096;
#pragma unroll
    for (int qq = 0; qq < 2; ++qq) {
      const int f = tid * 2 + qq;
      const int sp = f >> 7, half = (f >> 6) & 1, l = f & 63;
      ushort8 u;
      if (isK) {
        // K frag: row = half*32 + (l&31), d0 = sp*16 + (l>>5)*8  (row-contiguous)
        u = *reinterpret_cast<const ushort8*>(&t[half * 32 + (l & 31)][sp * 16 + (l >> 5) * 8]);
      } else {
        // V frag: kv0 = sp*16 + (l>>5)*8, d = half*32 + (l&31)  (column gather)
        const int kv0 = sp * 16 + (l >> 5) * 8, d = half * 32 + (l & 31);
#pragma unroll
        for (int j = 0; j < 8; ++j) u[j] = t[kv0 + j][d];
      }
      *reinterpret_cast<ushort8*>(dst + (size_t)f * 8) = u;
    }
  } else {
    int g = (bx - 2048) * 256 + tid;
    int lane = g & 63;
    int v = M[(size_t)g];
    u64 bits = __ballot(v != 0);
    if (lane == 0) Mb[g >> 6] = bits;
  }
}

// ---------------- main kernel (v9) ----------------
// Swapped-operand 32x32 MFMA, in-register softmax (no row-max), DEPTH=4
// pipelined gl16 staging with counted vmcnt, FRAGMENT-LINEAR LDS layout:
// every ds_read_b128 is base + lane*16 -> conflict-free.
// gl16 rule (m104/m108): LDS dest = wave-uniform base + lane*16 (readfirstlane);
// global SOURCE must carry the per-lane offset (tid*8) -- that was the v8 bug.
static __device__ __forceinline__ void iter_body(
    const u16* kb, const u16* vb, u64 mw,
    const bf16x8* Qf, f32x16& accOT0, f32x16& accOT1, float& l_,
    int lane, int hi) {
  const u32 mlo = (u32)mw, mhiw = (u32)(mw >> 32);

  // ---- QK^T (swapped): sT = K[tile] x Q^T, D[kv][q] ----
  f32x16 sT0 = {0,0,0,0,0,0,0,0,0,0,0,0,0,0,0,0};
  f32x16 sT1 = {0,0,0,0,0,0,0,0,0,0,0,0,0,0,0,0};
  __builtin_amdgcn_s_setprio(1);
#pragma unroll
  for (int s = 0; s < 4; ++s) {
    bf16x8 k0 = *reinterpret_cast<const bf16x8*>(kb + s * 1024 + lane * 8);
    bf16x8 k1 = *reinterpret_cast<const bf16x8*>(kb + s * 1024 + 512 + lane * 8);
    sT0 = __builtin_amdgcn_mfma_f32_32x32x16_bf16(k0, Qf[s], sT0, 0, 0, 0);
    sT1 = __builtin_amdgcn_mfma_f32_32x32x16_bf16(k1, Qf[s], sT1, 0, 0, 0);
  }
  __builtin_amdgcn_s_setprio(0);

  // ---- p = exp2(s), mask via sbfe+and, sum, pack to bf16 ----
  float lp0 = 0.f, lp1 = 0.f;
  u32 A0_[8], A1_[8];
#pragma unroll
  for (int T = 0; T < 2; ++T) {
    const f32x16& sv = T ? sT1 : sT0;
    const u32 mword = T ? mhiw : mlo;
#pragma unroll
    for (int j = 0; j < 8; ++j) {
      const int r0 = 2 * j, r1 = 2 * j + 1;
      const int b0 = (r0 & 3) + 8 * (r0 >> 2) + 4 * hi;
      const int b1 = (r1 & 3) + 8 * (r1 >> 2) + 4 * hi;
      float e0 = __builtin_amdgcn_exp2f(sv[r0]);
      float e1 = __builtin_amdgcn_exp2f(sv[r1]);
      int s0 = __builtin_amdgcn_sbfe(mword, b0, 1);
      int s1 = __builtin_amdgcn_sbfe(mword, b1, 1);
      e0 = __builtin_bit_cast(float, __builtin_bit_cast(u32, e0) & (u32)s0);
      e1 = __builtin_bit_cast(float, __builtin_bit_cast(u32, e1) & (u32)s1);
      lp0 += e0; lp1 += e1;
      u32 w = cvtpk(e0, e1);
      if (T == 0) A0_[j] = w; else A1_[j] = w;
    }
  }
  l_ += lp0 + lp1;

  // ---- build PV B-fragments in-register (distinct-operand permlane swaps) ----
  bf16x8 PA[4];
  {
    u32 a, c, b2, d2;
    a = A0_[0]; c = A0_[2]; plswap(a, c);
    b2 = A0_[1]; d2 = A0_[3]; plswap(b2, d2);
    u32x4 w0 = {a, b2, c, d2}; PA[0] = __builtin_bit_cast(bf16x8, w0);
    a = A0_[4]; c = A0_[6]; plswap(a, c);
    b2 = A0_[5]; d2 = A0_[7]; plswap(b2, d2);
    u32x4 w1 = {a, b2, c, d2}; PA[1] = __builtin_bit_cast(bf16x8, w1);
    a = A1_[0]; c = A1_[2]; plswap(a, c);
    b2 = A1_[1]; d2 = A1_[3]; plswap(b2, d2);
    u32x4 w2 = {a, b2, c, d2}; PA[2] = __builtin_bit_cast(bf16x8, w2);
    a = A1_[4]; c = A1_[6]; plswap(a, c);
    b2 = A1_[5]; d2 = A1_[7]; plswap(b2, d2);
    u32x4 w3 = {a, b2, c, d2}; PA[3] = __builtin_bit_cast(bf16x8, w3);
  }

  // ---- PV (swapped): accOT[D0] += V^T[D0-tile] x P^T ----
  __builtin_amdgcn_s_setprio(1);
#pragma unroll
  for (int ks = 0; ks < 4; ++ks) {
    bf16x8 v0 = *reinterpret_cast<const bf16x8*>(vb + ks * 1024 + lane * 8);
    bf16x8 v1 = *reinterpret_cast<const bf16x8*>(vb + ks * 1024 + 512 + lane * 8);
    accOT0 = __builtin_amdgcn_mfma_f32_32x32x16_bf16(v0, PA[ks], accOT0, 0, 0, 0);
    accOT1 = __builtin_amdgcn_mfma_f32_32x32x16_bf16(v1, PA[ks], accOT1, 0, 0, 0);
  }
  __builtin_amdgcn_s_setprio(0);
}

__global__ __launch_bounds__(256, 2) void attn_fwd9(
    const float* __restrict__ Q, const u16* __restrict__ Kf,
    const u16* __restrict__ Vf, const u64* __restrict__ Mb,
    float* __restrict__ O) {
  __shared__ __align__(16) u16 LB[32768];   // K bufs [4][4096] u16; V bufs +16384

  const int tid  = threadIdx.x;
  const int lane = tid & 63;
  const int wid  = tid >> 6;
  const int l31  = lane & 31;
  const int hi   = lane >> 5;

  const int bh = blockIdx.y, b = bh >> 4;
  const int q0w = blockIdx.x * 128 + wid * 32;
  const size_t base = (size_t)bh * SD;

  // Q fragments: f32 load + scale + pack (once per block)
  bf16x8 Qf[4];
  {
    const float* qsrc = Q + base + (size_t)(q0w + l31) * 64;
#pragma unroll
    for (int s = 0; s < 4; ++s) {
      const int d0 = s * 16 + hi * 8;
      float4 x = *reinterpret_cast<const float4*>(qsrc + d0);
      float4 y = *reinterpret_cast<const float4*>(qsrc + d0 + 4);
      u32x4 w;
      w[0] = cvtpk(x.x * QSCALE, x.y * QSCALE);
      w[1] = cvtpk(x.z * QSCALE, x.w * QSCALE);
      w[2] = cvtpk(y.x * QSCALE, y.y * QSCALE);
      w[3] = cvtpk(y.z * QSCALE, y.w * QSCALE);
      Qf[s] = __builtin_bit_cast(bf16x8, w);
    }
  }

  // staging source base (fragment-linear; per-lane offset tid*8 added in STAGE)
  const u16* kfA = Kf + (size_t)bh * FR_BH;
  const u16* vfA = Vf + (size_t)bh * FR_BH;

  const u64* mp = Mb + (size_t)b * MB_PB + (size_t)(q0w + l31) * MROW;

  f32x16 accOT0 = {0,0,0,0,0,0,0,0,0,0,0,0,0,0,0,0};
  f32x16 accOT1 = {0,0,0,0,0,0,0,0,0,0,0,0,0,0,0,0};
  float l_ = 0.f;

#define STAGE(buf, it) do {                                                                  \
    gl16(kfA + (size_t)(it) * 4096 + tid * 8,        LB + (buf) * 4096 + tid * 8);           \
    gl16(kfA + (size_t)(it) * 4096 + 2048 + tid * 8, LB + (buf) * 4096 + 2048 + tid * 8);    \
    gl16(vfA + (size_t)(it) * 4096 + tid * 8,        LB + 16384 + (buf) * 4096 + tid * 8);   \
    gl16(vfA + (size_t)(it) * 4096 + 2048 + tid * 8, LB + 16384 + (buf) * 4096 + 2048 + tid * 8); \
  } while (0)

#define BODY(IT, J, WN, DOSTAGE) do {                                    \
    WAITV(WN);                                                            \
    __builtin_amdgcn_s_barrier();                                         \
    __builtin_amdgcn_sched_barrier(0);                                    \
    if (DOSTAGE) { STAGE((((J) + 3) & 3), (IT) + 3); }                    \
    iter_body(LB + (J) * 4096, LB + 16384 + (J) * 4096, cm[J],            \
              Qf, accOT0, accOT1, l_, lane, hi);                          \
  } while (0)

  u64 cm[4], nm[4];
  cm[0] = mp[0]; cm[1] = mp[1]; cm[2] = mp[2]; cm[3] = mp[3];
  STAGE(0, 0); STAGE(1, 1); STAGE(2, 2);

#pragma unroll 1
  for (int g = 0; g < 7; ++g) {
    const int it0 = g * 4;
    nm[0] = mp[it0 + 4]; nm[1] = mp[it0 + 5];
    nm[2] = mp[it0 + 6]; nm[3] = mp[it0 + 7];
    BODY(it0 + 0, 0, 8, true);
    BODY(it0 + 1, 1, 8, true);
    BODY(it0 + 2, 2, 8, true);
    BODY(it0 + 3, 3, 8, true);
    cm[0] = nm[0]; cm[1] = nm[1]; cm[2] = nm[2]; cm[3] = nm[3];
  }
  // tail: it = 28..31 (body 28 stages tile 31; stages-only counted waits)
  BODY(28, 0, 8, true);
  BODY(29, 1, 8, false);
  BODY(30, 2, 4, false);
  BODY(31, 3, 0, false);

  __syncthreads();   // protect LDS reuse by epilogue across waves

  // ---- epilogue: l across halves, normalize, LDS-bounce transpose, store ----
  l_ += __shfl_xor(l_, 32);
  const float inv = __builtin_amdgcn_rcpf(l_);

  float* Sc = (float*)((char*)LB + wid * 4608);   // per-wave [32][36] f32
#pragma unroll
  for (int D0 = 0; D0 < 2; ++D0) {
    const f32x16& acc = D0 ? accOT1 : accOT0;
#pragma unroll
    for (int r = 0; r < 16; ++r) {
      const int dloc = (r & 3) + 8 * (r >> 2) + 4 * hi;
      Sc[l31 * 36 + dloc] = acc[r] * inv;
    }
    asm volatile("s_waitcnt lgkmcnt(0)" ::: "memory");
    __builtin_amdgcn_sched_barrier(0);
    const int qq = lane >> 1, off = (lane & 1) * 16;
#pragma unroll
    for (int j = 0; j < 4; ++j) {
      float4 x = *reinterpret_cast<const float4*>(&Sc[qq * 36 + off + j * 4]);
      *reinterpret_cast<float4*>(O + base + (size_t)(q0w + qq) * 64 + D0 * 32 + off + j * 4) = x;
    }
    asm volatile("s_waitcnt lgkmcnt(0)" ::: "memory");
    __builtin_amdgcn_sched_barrier(0);
  }
#undef STAGE
#undef BODY
}

// ---------------- fallback (round-1 kernel, used if ws too small) ----------------
#define KST 72
#define VST 40
#define PST 40
static __device__ __forceinline__ bf16x8 ld_frag(const u16* p) {
  ushort8 u = *reinterpret_cast<const ushort8*>(p);
  return __builtin_bit_cast(bf16x8, u);
}
__global__ __launch_bounds__(256) void attn_fwd_v1(
    const float* __restrict__ Q, const float* __restrict__ K,
    const float* __restrict__ V, const int* __restrict__ M,
    float* __restrict__ O) {
  __shared__ __align__(16) u16 Klds[32 * KST];
  __shared__ __align__(16) u16 Vlds[64 * VST];
  __shared__ __align__(16) u16 Plds[4 * 16 * PST];
  const int tid = threadIdx.x, lane = tid & 63, wid = tid >> 6;
  const int lrow = lane & 15, lgrp = lane >> 4;
  const int bh = blockIdx.y, b = bh >> 4;
  const int q0 = blockIdx.x * 64 + wid * 16;
  const int base = bh * S_LEN * D_DIM, mbase = b * S_LEN * S_LEN;
  bf16x8 qf[2];
#pragma unroll
  for (int c = 0; c < 2; ++c) {
    const float* src = Q + base + (q0 + lrow) * 64 + c * 32 + lgrp * 8;
    float4 x = *reinterpret_cast<const float4*>(src);
    float4 y = *reinterpret_cast<const float4*>(src + 4);
    ushort8 u;
    u[0]=f2bf(x.x*0.125f); u[1]=f2bf(x.y*0.125f); u[2]=f2bf(x.z*0.125f); u[3]=f2bf(x.w*0.125f);
    u[4]=f2bf(y.x*0.125f); u[5]=f2bf(y.y*0.125f); u[6]=f2bf(y.z*0.125f); u[7]=f2bf(y.w*0.125f);
    qf[c] = __builtin_bit_cast(bf16x8, u);
  }
  f32x4 accO[4];
#pragma unroll
  for (int c = 0; c < 4; ++c) accO[c] = (f32x4){0.f,0.f,0.f,0.f};
  float m_[4] = {-1e9f,-1e9f,-1e9f,-1e9f}, l_[4] = {0.f,0.f,0.f,0.f};
  const int srow = tid >> 3, scol = (tid & 7) * 8;
  for (int kv0 = 0; kv0 < S_LEN; kv0 += 32) {
    __syncthreads();
    {
      const float* src = K + base + (kv0 + srow) * 64 + scol;
      float4 x = *reinterpret_cast<const float4*>(src);
      float4 y = *reinterpret_cast<const float4*>(src + 4);
      ushort8 u;
      u[0]=f2bf(x.x); u[1]=f2bf(x.y); u[2]=f2bf(x.z); u[3]=f2bf(x.w);
      u[4]=f2bf(y.x); u[5]=f2bf(y.y); u[6]=f2bf(y.z); u[7]=f2bf(y.w);
      *reinterpret_cast<ushort8*>(&Klds[srow * KST + scol]) = u;
    }
    {
      const float* src = V + base + (kv0 + srow) * 64 + scol;
      float4 x = *reinterpret_cast<const float4*>(src);
      float4 y = *reinterpret_cast<const float4*>(src + 4);
      float vals[8] = {x.x,x.y,x.z,x.w,y.x,y.y,y.z,y.w};
#pragma unroll
      for (int i = 0; i < 8; ++i) Vlds[(scol + i) * VST + srow] = f2bf(vals[i]);
    }
    __syncthreads();
    f32x4 s0 = (f32x4){0.f,0.f,0.f,0.f}, s1 = (f32x4){0.f,0.f,0.f,0.f};
#pragma unroll
    for (int c = 0; c < 2; ++c) {
      bf16x8 k0 = ld_frag(&Klds[lrow * KST + c * 32 + lgrp * 8]);
      bf16x8 k1 = ld_frag(&Klds[(16 + lrow) * KST + c * 32 + lgrp * 8]);
      s0 = __builtin_amdgcn_mfma_f32_16x16x32_bf16(qf[c], k0, s0, 0, 0, 0);
      s1 = __builtin_amdgcn_mfma_f32_16x16x32_bf16(qf[c], k1, s1, 0, 0, 0);
    }
#pragma unroll
    for (int r = 0; r < 4; ++r) {
      const int moff = mbase + (q0 + lgrp * 4 + r) * S_LEN + kv0 + lrow;
      if (M[moff] == 0)      s0[r] = -1e30f;
      if (M[moff + 16] == 0) s1[r] = -1e30f;
    }
    const int pbase = wid * 16 * PST;
#pragma unroll
    for (int r = 0; r < 4; ++r) {
      float t = fmaxf(s0[r], s1[r]);
      t = fmaxf(t, __shfl_xor(t, 1)); t = fmaxf(t, __shfl_xor(t, 2));
      t = fmaxf(t, __shfl_xor(t, 4)); t = fmaxf(t, __shfl_xor(t, 8));
      float mn = fmaxf(m_[r], t);
      float sf = __expf(m_[r] - mn);
      m_[r] = mn;
      float p0 = __expf(s0[r] - mn), p1 = __expf(s1[r] - mn);
      float su = p0 + p1;
      su += __shfl_xor(su, 1); su += __shfl_xor(su, 2);
      su += __shfl_xor(su, 4); su += __shfl_xor(su, 8);
      l_[r] = l_[r] * sf + su;
      accO[0][r] *= sf; accO[1][r] *= sf; accO[2][r] *= sf; accO[3][r] *= sf;
      const int prow = lgrp * 4 + r;
      Plds[pbase + prow * PST + lrow]      = f2bf(p0);
      Plds[pbase + prow * PST + 16 + lrow] = f2bf(p1);
    }
    asm volatile("s_waitcnt lgkmcnt(0)" ::: "memory");
    __builtin_amdgcn_sched_barrier(0);
    bf16x8 pa = ld_frag(&Plds[pbase + lrow * PST + lgrp * 8]);
#pragma unroll
    for (int c = 0; c < 4; ++c) {
      bf16x8 bv = ld_frag(&Vlds[(c * 16 + lrow) * VST + lgrp * 8]);
      accO[c] = __builtin_amdgcn_mfma_f32_16x16x32_bf16(pa, bv, accO[c], 0, 0, 0);
    }
  }
#pragma unroll
  for (int r = 0; r < 4; ++r) {
    const float inv = 1.0f / l_[r];
    float* dst = O + base + (q0 + lgrp * 4 + r) * 64;
#pragma unroll
    for (int c = 0; c < 4; ++c) dst[c * 16 + lrow] = accO[c][r] * inv;
  }
}

extern "C" void kernel_launch(void* const* d_in, const int* in_sizes, int n_in,
                              void* d_out, int out_size, void* d_ws, size_t ws_size,
                              hipStream_t stream) {
  const float* q = (const float*)d_in[0];
  const float* k = (const float*)d_in[1];
  const float* v = (const float*)d_in[2];
  const int*   m = (const int*)d_in[3];
  float* out = (float*)d_out;

  if (ws_size < (size_t)WS_NEED) {
    dim3 grid(S_LEN / 64, NBH);
    attn_fwd_v1<<<grid, dim3(256), 0, stream>>>(q, k, v, m, out);
    return;
  }

  u16* Kf = (u16*)((char*)d_ws + KF_OFF);
  u16* Vf = (u16*)((char*)d_ws + VF_OFF);
  u64* Mb = (u64*)((char*)d_ws + MB_OFF);

  prep_all<<<dim3(34816), dim3(256), 0, stream>>>(k, v, m, Kf, Vf, Mb);
  attn_fwd9<<<dim3(S_LEN / 128, NBH), dim3(256), 0, stream>>>(q, Kf, Vf, Mb, out);
}